// Round 1
// 565.621 us; speedup vs baseline: 1.1212x; 1.1212x over previous
//
#include <hip/hip_runtime.h>
#include <math.h>

// b=16, c=64, N=65536 fp32.
// out[b,c,n] = sum_d A'[b,c,d] * x[b,d,n],  A' = gamma*softmax(min-att)+I,
// att = Q Q^T (Q = x reshaped [b,64,N]).
// ws floats: [0, 512*4096) gram partials (8 MB); then 16*4096 A'^T ([b][d][c]).

#define CH 64
#define NPIX 65536

typedef __bf16 bf16x8 __attribute__((ext_vector_type(8)));
typedef float f32x16 __attribute__((ext_vector_type(16)));

// ---------------- Kernel 1: partial Gram via MFMA (bf16 hi/lo split) --------
// grid (32,16), block 256 = 4 waves. Block owns 2048 px, staged in 16 tiles of
// 128 px, double-buffered. x fp32 -> H=bf16(x), L=bf16(x-H) at staging time.
// Wave w computes 32x32 output tile (i=w>>1, j=w&1):
//   P(i,j) = 0.5*H_i H_j^T + H_i L_j^T   (2 MFMAs / 16-px k-step)
// Final G-partial = P + P^T via in-LDS tile transpose exchange (exact since
// HH^T is symmetric and HL^T/LH^T terms pair across the diagonal).
// LDS planes XOR-16 swizzled: group16B' = g ^ (row&15) -> uniform bank load
// for both the b128 fragment reads and the b64 staging writes.
// MFMA k-slot permutation is irrelevant: A and B fragments are built with the
// identical (lane,reg)->pixel mapping, and QQ^T only needs consistency.
__global__ __launch_bounds__(256, 2) void ca_gram_kernel(
    const float* __restrict__ x, float* __restrict__ partials) {
  __shared__ unsigned short Hp[2][64 * 128];   // 32 KiB: bf16 hi plane
  __shared__ unsigned short Lp[2][64 * 128];   // 32 KiB: bf16 lo plane
  const int b    = blockIdx.y;
  const int tid  = threadIdx.x;
  const int wave = tid >> 6;
  const int lane = tid & 63;
  const int r    = lane & 31;        // MFMA row/col within tile
  const int half = lane >> 5;        // k-group half
  const int ti   = wave >> 1, tj = wave & 1;
  const float* qb = x + (size_t)b * CH * NPIX;
  const int px0 = blockIdx.x * 2048;
  const int sc  = tid >> 5;          // staging: row within 8-row round (0..7)
  const int sp  = (tid & 31) * 4;    // staging: pixel offset (0..124)

  f32x16 accHH, accHL;
#pragma unroll
  for (int q = 0; q < 16; ++q) { accHH[q] = 0.f; accHL[q] = 0.f; }

  float4 pre[8];
#pragma unroll
  for (int i2 = 0; i2 < 8; ++i2)
    pre[i2] = *(const float4*)(qb + (size_t)(i2 * 8 + sc) * NPIX + px0 + sp);

  const int rowA = ti * 32 + r;
  const int rowB = tj * 32 + r;

  for (int t = 0; t < 16; ++t) {
    unsigned short* hw = Hp[t & 1];
    unsigned short* lw = Lp[t & 1];
    // ---- convert fp32 -> (H,L) bf16 and stage into LDS (swizzled) ----
#pragma unroll
    for (int i2 = 0; i2 < 8; ++i2) {
      const int c = i2 * 8 + sc;
      const float vv[4] = {pre[i2].x, pre[i2].y, pre[i2].z, pre[i2].w};
      unsigned int hb[4], lb[4];
#pragma unroll
      for (int e = 0; e < 4; ++e) {
        const unsigned int u = __float_as_uint(vv[e]);
        hb[e] = (u + 0x7FFFu + ((u >> 16) & 1u)) >> 16;              // RNE bf16
        const float lf = vv[e] - __uint_as_float(hb[e] << 16);       // exact
        const unsigned int ul = __float_as_uint(lf);
        lb[e] = (ul + 0x7FFFu + ((ul >> 16) & 1u)) >> 16;
      }
      const int g   = sp >> 3;                                        // 16B group
      const int off = c * 128 + (((g ^ (c & 15)) << 3) | (sp & 7));
      *(uint2*)(hw + off) = make_uint2(hb[0] | (hb[1] << 16), hb[2] | (hb[3] << 16));
      *(uint2*)(lw + off) = make_uint2(lb[0] | (lb[1] << 16), lb[2] | (lb[3] << 16));
    }
    __syncthreads();   // single barrier per stage (dbuf covers the other hazard)

    // ---- issue next tile's global loads; land during compute below ----
    if (t < 15) {
#pragma unroll
      for (int i2 = 0; i2 < 8; ++i2)
        pre[i2] = *(const float4*)(qb + (size_t)(i2 * 8 + sc) * NPIX + px0 +
                                   (t + 1) * 128 + sp);
    }

    // ---- 8 k-steps of 16 px: 3 ds_read_b128 (2 on diagonal) + 2 MFMA ----
    const unsigned short* hr = Hp[t & 1];
    const unsigned short* lr = Lp[t & 1];
#pragma unroll
    for (int ks = 0; ks < 8; ++ks) {
      const int g = ks * 2 + half;
      const bf16x8 aH = *(const bf16x8*)(hr + rowA * 128 + ((g ^ (rowA & 15)) << 3));
      bf16x8 bH;
      if (ti == tj) bH = aH;   // wave-uniform branch
      else bH = *(const bf16x8*)(hr + rowB * 128 + ((g ^ (rowB & 15)) << 3));
      const bf16x8 bL = *(const bf16x8*)(lr + rowB * 128 + ((g ^ (rowB & 15)) << 3));
      accHH = __builtin_amdgcn_mfma_f32_32x32x16_bf16(aH, bH, accHH, 0, 0, 0);
      accHL = __builtin_amdgcn_mfma_f32_32x32x16_bf16(aH, bL, accHL, 0, 0, 0);
    }
  }

  // ---- epilogue: P = 0.5*HH + HL; G-partial = P + P^T via LDS exchange ----
  // C/D layout (HW-verified): col = lane&31, row = (q&3) + 8*(q>>2) + 4*half.
  float mine[16];
#pragma unroll
  for (int q = 0; q < 16; ++q) mine[q] = 0.5f * accHH[q] + accHL[q];
  float* ep = (float*)&Hp[0][0];   // 16 KiB: 4 tiles x 1024 floats (safe: last
                                   // compute reads hit buf 1 only)
#pragma unroll
  for (int q = 0; q < 16; ++q) {
    const int row = (q & 3) + 8 * (q >> 2) + 4 * half;
    ep[wave * 1024 + row * 32 + (r ^ row)] = mine[q];   // XOR anti-conflict
  }
  __syncthreads();
  const int ptile = tj * 2 + ti;   // transpose-partner wave
  float* outp = partials + (size_t)(b * 32 + blockIdx.x) * 4096;
#pragma unroll
  for (int q = 0; q < 16; ++q) {
    const int row = (q & 3) + 8 * (q >> 2) + 4 * half;
    const float theirs = ep[ptile * 1024 + r * 32 + (row ^ r)];  // P(j,i)[r][row]
    outp[(32 * ti + row) * 64 + 32 * tj + r] = mine[q] + theirs;
  }
}

// ---------------- Kernel 2: reduce + reversed softmax -> A'^T ----------------
// grid (64,16), block 64: one wave per (b,c) row; lane = d.
// Writes A'^T[b][d][c] = gamma*softmax_row(c)[d] + (c==d).
__global__ void ca_softmax_kernel(const float* __restrict__ partials,
                                  const float* __restrict__ gamma,
                                  float* __restrict__ ApT) {
  const int b = blockIdx.y, c = blockIdx.x, d = threadIdx.x;
  const float* p = partials + (size_t)b * 32 * 4096 + c * 64 + d;
  float s = 0.f;
#pragma unroll
  for (int kk = 0; kk < 32; ++kk) s += p[(size_t)kk * 4096];
  // reversed softmax == exp(min_row - att) / sum
  float mn = s;
#pragma unroll
  for (int off = 32; off > 0; off >>= 1) mn = fminf(mn, __shfl_down(mn, off));
  mn = __shfl(mn, 0);
  const float w = expf(mn - s);
  float sum = w;
#pragma unroll
  for (int off = 32; off > 0; off >>= 1) sum += __shfl_down(sum, off);
  sum = __shfl(sum, 0);
  const float v = gamma[0] * (w / sum) + (c == d ? 1.f : 0.f);
  ApT[((size_t)b * 64 + d) * 64 + c] = v;   // transposed for apply kernel
}

// ---------------- Kernel 3: out[b,c,n] = sum_d A'[c,d] x[b,d,n] --------------
// grid (256,16), block 256 = 4 waves. Block owns 256 consecutive pixels.
// Wave w -> channels [16w,16w+16); lane -> 4 consecutive pixels.
// acc = 16 float4 (64 VGPRs). x: coalesced dwordx4. A'^T: LDS b128 broadcast.
__global__ __launch_bounds__(256, 2) void ca_apply_kernel(
    const float* __restrict__ x, const float* __restrict__ ApT,
    float* __restrict__ out) {
  __shared__ float At[4096];                 // [d][c], 16 KiB
  const int b    = blockIdx.y;
  const int tid  = threadIdx.x;
  const int wave = tid >> 6;
  const int lane = tid & 63;
  const int c0   = wave * 16;

  const float* src = ApT + (size_t)b * 4096;
#pragma unroll
  for (int i = 0; i < 4; ++i)
    ((float4*)At)[tid + 256 * i] = ((const float4*)src)[tid + 256 * i];
  __syncthreads();

  const size_t pix = (size_t)blockIdx.x * 256 + lane * 4;
  const float* xb = x + (size_t)b * CH * NPIX + pix;
  float4 acc[16];
#pragma unroll
  for (int c = 0; c < 16; ++c) acc[c] = make_float4(0.f, 0.f, 0.f, 0.f);

  for (int d0 = 0; d0 < 64; d0 += 4) {
    float4 xv[4];
#pragma unroll
    for (int j = 0; j < 4; ++j)
      xv[j] = *(const float4*)(xb + (size_t)(d0 + j) * NPIX);
#pragma unroll
    for (int j = 0; j < 4; ++j) {
#pragma unroll
      for (int q = 0; q < 4; ++q) {
        const float4 a = *(const float4*)(At + (d0 + j) * 64 + c0 + q * 4);  // broadcast
        const float av[4] = {a.x, a.y, a.z, a.w};
#pragma unroll
        for (int e = 0; e < 4; ++e) {
          float4& A4 = acc[q * 4 + e];
          A4.x = fmaf(av[e], xv[j].x, A4.x);
          A4.y = fmaf(av[e], xv[j].y, A4.y);
          A4.z = fmaf(av[e], xv[j].z, A4.z);
          A4.w = fmaf(av[e], xv[j].w, A4.w);
        }
      }
    }
  }
  float* ob = out + (size_t)b * CH * NPIX + pix;
#pragma unroll
  for (int c = 0; c < 16; ++c)
    *(float4*)(ob + (size_t)(c0 + c) * NPIX) = acc[c];
}

extern "C" void kernel_launch(void* const* d_in, const int* in_sizes, int n_in,
                              void* d_out, int out_size, void* d_ws, size_t ws_size,
                              hipStream_t stream) {
  const float* x     = (const float*)d_in[0];
  const float* gamma = (const float*)d_in[1];
  float* out      = (float*)d_out;
  float* partials = (float*)d_ws;                    // 512*4096 floats = 8 MB
  float* ApT      = partials + (size_t)512 * 4096;   // 16*4096 floats

  ca_gram_kernel<<<dim3(32, 16), 256, 0, stream>>>(x, partials);
  ca_softmax_kernel<<<dim3(64, 16), 64, 0, stream>>>(partials, gamma, ApT);
  ca_apply_kernel<<<dim3(256, 16), 256, 0, stream>>>(x, ApT, out);
}

// Round 2
// 552.287 us; speedup vs baseline: 1.1482x; 1.0241x over previous
//
#include <hip/hip_runtime.h>
#include <math.h>

// b=16, c=64, N=65536 fp32.
// out[b,c,n] = sum_d A'[b,c,d] * x[b,d,n],  A' = gamma*softmax(min-att)+I,
// att = Q Q^T (Q = x reshaped [b,64,N]).
// ws floats: [0, 512*4096) gram partials (8 MB); then 16*4096 A'^T ([b][d][c]).

#define CH 64
#define NPIX 65536
#define PITCH 48   // u16 per LDS tile row (16-B aligned; uniform-bank swizzle)

typedef __bf16 bf16x8 __attribute__((ext_vector_type(8)));
typedef float f32x4 __attribute__((ext_vector_type(4)));

// ---------------- Kernel 1: partial Gram via MFMA, wave-private, no barriers -
// grid (32,16), block 256 = 4 waves. Wave w owns px strip [2048*bx + 512*w ..),
// processed in 16 rounds of 32 px. Per round: 8 coalesced float4 loads ->
// convert x -> H=bf16(x), L2=bf16(2*(x-H)) -> LDS (single wave-private tile,
// in-order DS makes this race-free with NO barriers) -> one 16x16x32-MFMA
// k-step: P' = H H^T + H L2^T over all 16 (i,j) 16x16 tiles (acc 64 VGPR).
// G_partial = 0.5*(P' + P'^T) summed over waves in a 2-barrier epilogue.
// Dropped term 0.25*L2 L2^T ~ 2^-16 relative (identical math to prior round).
// LDS tile: row pitch 48 u16; 16-B granule g stored at g^(row&3) -> both b64
// writes and b128 frag reads hit every bank with exactly minimum cycles.
__global__ __launch_bounds__(256, 2) void ca_gram_kernel(
    const float* __restrict__ x, float* __restrict__ partials) {
  __shared__ __align__(16) unsigned char smem[65536];  // tiles (48K) / ep (64K)
  const int b    = blockIdx.y;
  const int tid  = threadIdx.x;
  const int wave = tid >> 6;
  const int lane = tid & 63;
  // staging lane map
  const int cho    = lane >> 3;          // ch sub-row (0..7)
  const int px_off = (lane & 7) * 4;     // 4 consecutive px
  const int gw     = px_off >> 3;        // 16-B granule (0..3)
  const int ha     = px_off & 4;         // 8-B half within granule
  // fragment lane map (16x16x32: row/col = lane&15, k-group = lane>>4)
  const int r16 = lane & 15;
  const int g16 = lane >> 4;

  unsigned short* Ht = (unsigned short*)smem + wave * (2 * 64 * PITCH);
  unsigned short* Lt = Ht + 64 * PITCH;

  const float* qb = x + (size_t)b * CH * NPIX;
  const size_t px_base = (size_t)blockIdx.x * 2048 + wave * 512;

  f32x4 acc[4][4];
#pragma unroll
  for (int i = 0; i < 4; ++i)
#pragma unroll
    for (int j = 0; j < 4; ++j) acc[i][j] = (f32x4)(0.f);

  float4 pre[8];
#pragma unroll
  for (int m = 0; m < 8; ++m)
    pre[m] = *(const float4*)(qb + (size_t)(m * 8 + cho) * NPIX + px_base + px_off);

  for (int s = 0; s < 16; ++s) {
    // ---- convert + stage round s (wave-private; no barrier needed) ----
#pragma unroll
    for (int m = 0; m < 8; ++m) {
      const int ch = m * 8 + cho;
      const float vv[4] = {pre[m].x, pre[m].y, pre[m].z, pre[m].w};
      unsigned short hu[4], lu[4];
#pragma unroll
      for (int e = 0; e < 4; ++e) {
        const __bf16 hb = (__bf16)vv[e];                       // RNE
        const float  hf = (float)hb;                           // exact
        const __bf16 lb = (__bf16)(2.f * (vv[e] - hf));        // L2 = 2L
        hu[e] = __builtin_bit_cast(unsigned short, hb);
        lu[e] = __builtin_bit_cast(unsigned short, lb);
      }
      const int wa = ch * PITCH + (((gw ^ (ch & 3)) << 3) | ha);
      *(uint2*)(Ht + wa) = make_uint2(hu[0] | (hu[1] << 16), hu[2] | (hu[3] << 16));
      *(uint2*)(Lt + wa) = make_uint2(lu[0] | (lu[1] << 16), lu[2] | (lu[3] << 16));
    }
    // ---- issue next round's loads; land under MFMA + later waves ----
    if (s < 15) {
#pragma unroll
      for (int m = 0; m < 8; ++m)
        pre[m] = *(const float4*)(qb + (size_t)(m * 8 + cho) * NPIX + px_base +
                                  (s + 1) * 32 + px_off);
    }
    // ---- one 16x16x32 k-step over the 32-px tile ----
    bf16x8 aH[4], aL[4];
#pragma unroll
    for (int i = 0; i < 4; ++i) {
      const int ra = (i * 16 + r16) * PITCH + ((g16 ^ (r16 & 3)) << 3);
      aH[i] = *(const bf16x8*)(Ht + ra);
      aL[i] = *(const bf16x8*)(Lt + ra);
    }
#pragma unroll
    for (int i = 0; i < 4; ++i)
#pragma unroll
      for (int j = 0; j < 4; ++j) {
        acc[i][j] = __builtin_amdgcn_mfma_f32_16x16x32_bf16(aH[i], aH[j], acc[i][j], 0, 0, 0);
        acc[i][j] = __builtin_amdgcn_mfma_f32_16x16x32_bf16(aH[i], aL[j], acc[i][j], 0, 0, 0);
      }
  }

  // ---- epilogue: G = 0.5*(P' + P'^T), cross-wave sum, one output/block ----
  __syncthreads();                       // all waves done with tile LDS
  float* ep = (float*)smem + wave * 4096;  // [64][64], cols xor-swizzled
#pragma unroll
  for (int i = 0; i < 4; ++i)
#pragma unroll
    for (int j = 0; j < 4; ++j)
#pragma unroll
      for (int q = 0; q < 4; ++q) {
        const int R = i * 16 + g16 * 4 + q;    // C/D layout (m89-verified)
        const int C = j * 16 + r16;
        ep[R * 64 + (C & 48) + ((C ^ R) & 15)] = acc[i][j][q];
      }
  __syncthreads();
  float* outp = partials + (size_t)(b * 32 + blockIdx.x) * 4096;
  for (int k = 0; k < 16; ++k) {
    const int idx = k * 256 + tid;
    const int r = idx >> 6, c = idx & 63;
    float ssum = 0.f;
#pragma unroll
    for (int w = 0; w < 4; ++w) {
      const float* epw = (float*)smem + w * 4096;
      ssum += epw[r * 64 + (c & 48) + ((c ^ r) & 15)]    // P'(r,c)
            + epw[c * 64 + (r & 48) + ((r ^ c) & 15)];   // P'(c,r)
    }
    outp[idx] = 0.5f * ssum;
  }
}

// ---------------- Kernel 2: reduce + reversed softmax -> A'^T ----------------
// grid (64,16), block 64: one wave per (b,c) row; lane = d.
// Writes A'^T[b][d][c] = gamma*softmax_row(c)[d] + (c==d).
__global__ void ca_softmax_kernel(const float* __restrict__ partials,
                                  const float* __restrict__ gamma,
                                  float* __restrict__ ApT) {
  const int b = blockIdx.y, c = blockIdx.x, d = threadIdx.x;
  const float* p = partials + (size_t)b * 32 * 4096 + c * 64 + d;
  float s = 0.f;
#pragma unroll
  for (int kk = 0; kk < 32; ++kk) s += p[(size_t)kk * 4096];
  // reversed softmax == exp(min_row - att) / sum
  float mn = s;
#pragma unroll
  for (int off = 32; off > 0; off >>= 1) mn = fminf(mn, __shfl_down(mn, off));
  mn = __shfl(mn, 0);
  const float w = expf(mn - s);
  float sum = w;
#pragma unroll
  for (int off = 32; off > 0; off >>= 1) sum += __shfl_down(sum, off);
  sum = __shfl(sum, 0);
  const float v = gamma[0] * (w / sum) + (c == d ? 1.f : 0.f);
  ApT[((size_t)b * 64 + d) * 64 + c] = v;   // transposed for apply kernel
}

// ---------------- Kernel 3: out[b,c,n] = sum_d A'[c,d] x[b,d,n] --------------
// grid (256,16), block 256 = 4 waves. Block owns 256 consecutive pixels.
// Wave w -> channels [16w,16w+16); lane -> 4 consecutive pixels.
// acc = 16 float4 (64 VGPRs). x: coalesced dwordx4. A'^T: LDS b128 broadcast.
__global__ __launch_bounds__(256, 2) void ca_apply_kernel(
    const float* __restrict__ x, const float* __restrict__ ApT,
    float* __restrict__ out) {
  __shared__ float At[4096];                 // [d][c], 16 KiB
  const int b    = blockIdx.y;
  const int tid  = threadIdx.x;
  const int wave = tid >> 6;
  const int lane = tid & 63;
  const int c0   = wave * 16;

  const float* src = ApT + (size_t)b * 4096;
#pragma unroll
  for (int i = 0; i < 4; ++i)
    ((float4*)At)[tid + 256 * i] = ((const float4*)src)[tid + 256 * i];
  __syncthreads();

  const size_t pix = (size_t)blockIdx.x * 256 + lane * 4;
  const float* xb = x + (size_t)b * CH * NPIX + pix;
  float4 acc[16];
#pragma unroll
  for (int c = 0; c < 16; ++c) acc[c] = make_float4(0.f, 0.f, 0.f, 0.f);

  for (int d0 = 0; d0 < 64; d0 += 4) {
    float4 xv[4];
#pragma unroll
    for (int j = 0; j < 4; ++j)
      xv[j] = *(const float4*)(xb + (size_t)(d0 + j) * NPIX);
#pragma unroll
    for (int j = 0; j < 4; ++j) {
#pragma unroll
      for (int q = 0; q < 4; ++q) {
        const float4 a = *(const float4*)(At + (d0 + j) * 64 + c0 + q * 4);  // broadcast
        const float av[4] = {a.x, a.y, a.z, a.w};
#pragma unroll
        for (int e = 0; e < 4; ++e) {
          float4& A4 = acc[q * 4 + e];
          A4.x = fmaf(av[e], xv[j].x, A4.x);
          A4.y = fmaf(av[e], xv[j].y, A4.y);
          A4.z = fmaf(av[e], xv[j].z, A4.z);
          A4.w = fmaf(av[e], xv[j].w, A4.w);
        }
      }
    }
  }
  float* ob = out + (size_t)b * CH * NPIX + pix;
#pragma unroll
  for (int c = 0; c < 16; ++c)
    *(float4*)(ob + (size_t)(c0 + c) * NPIX) = acc[c];
}

extern "C" void kernel_launch(void* const* d_in, const int* in_sizes, int n_in,
                              void* d_out, int out_size, void* d_ws, size_t ws_size,
                              hipStream_t stream) {
  const float* x     = (const float*)d_in[0];
  const float* gamma = (const float*)d_in[1];
  float* out      = (float*)d_out;
  float* partials = (float*)d_ws;                    // 512*4096 floats = 8 MB
  float* ApT      = partials + (size_t)512 * 4096;   // 16*4096 floats

  ca_gram_kernel<<<dim3(32, 16), 256, 0, stream>>>(x, partials);
  ca_softmax_kernel<<<dim3(64, 16), 64, 0, stream>>>(partials, gamma, ApT);
  ca_apply_kernel<<<dim3(256, 16), 256, 0, stream>>>(x, ApT, out);
}